// Round 1
// baseline (426.233 us; speedup 1.0000x reference)
//
#include <hip/hip_runtime.h>
#include <math.h>

#define Nn 10000
#define INF_ 512
#define OUTF 64
#define ALPHA 0.2f
#define LOG2E 1.4426950408889634f

#define TI 32
#define TJ 64
#define NTILES ((Nn + TJ - 1) / TJ)   /* 157 */
#define TILES0 ((NTILES + 1) / 2)     /* 79  */

/* workspace layout (float offsets) */
#define WS_H    0
#define WS_S    (Nn * OUTF)           /* 640000 */
#define WS_T    (WS_S + Nn)           /* 650000 */
#define WS_TMAX (WS_T + Nn)           /* 660000 */
#define WS_DEN  (WS_TMAX + 16)        /* 660016 */

__device__ __forceinline__ void fma4(float4& a, float p, const float4& h) {
    a.x = fmaf(p, h.x, a.x); a.y = fmaf(p, h.y, a.y);
    a.z = fmaf(p, h.z, a.z); a.w = fmaf(p, h.w, a.w);
}

/* ---------------- kernel 1: h = x @ W, fused s = h@a_self, t = h@a_neighs ----- */
__global__ __launch_bounds__(256) void hgemm_kernel(
    const float* __restrict__ x, const float* __restrict__ W,
    const float* __restrict__ a_self, const float* __restrict__ a_neighs,
    float* __restrict__ h, float* __restrict__ s, float* __restrict__ t)
{
    const int col  = threadIdx.x & 63;
    const int wid  = threadIdx.x >> 6;            /* 0..3 */
    const int row0 = blockIdx.x * 16 + wid * 4;   /* 625 blocks * 16 rows = 10000 */
    const float* x0 = x + row0 * INF_;

    float acc0 = 0.f, acc1 = 0.f, acc2 = 0.f, acc3 = 0.f;
    #pragma unroll 4
    for (int k4 = 0; k4 < INF_ / 4; ++k4) {
        const int k = k4 << 2;
        const float w0 = W[(k    ) * OUTF + col];
        const float w1 = W[(k + 1) * OUTF + col];
        const float w2 = W[(k + 2) * OUTF + col];
        const float w3 = W[(k + 3) * OUTF + col];
        const float4 xa = *(const float4*)(x0 +            k);
        const float4 xb = *(const float4*)(x0 +   INF_   + k);
        const float4 xc = *(const float4*)(x0 + 2*INF_   + k);
        const float4 xd = *(const float4*)(x0 + 3*INF_   + k);
        acc0 = fmaf(xa.x,w0, fmaf(xa.y,w1, fmaf(xa.z,w2, fmaf(xa.w,w3, acc0))));
        acc1 = fmaf(xb.x,w0, fmaf(xb.y,w1, fmaf(xb.z,w2, fmaf(xb.w,w3, acc1))));
        acc2 = fmaf(xc.x,w0, fmaf(xc.y,w1, fmaf(xc.z,w2, fmaf(xc.w,w3, acc2))));
        acc3 = fmaf(xd.x,w0, fmaf(xd.y,w1, fmaf(xd.z,w2, fmaf(xd.w,w3, acc3))));
    }
    h[(row0+0)*OUTF + col] = acc0;
    h[(row0+1)*OUTF + col] = acc1;
    h[(row0+2)*OUTF + col] = acc2;
    h[(row0+3)*OUTF + col] = acc3;

    const float as = a_self[col], an = a_neighs[col];
    #define RED(ACC, U) { \
        float vs = (ACC) * as, vn = (ACC) * an; \
        _Pragma("unroll") \
        for (int d_ = 32; d_; d_ >>= 1) { vs += __shfl_xor(vs, d_); vn += __shfl_xor(vn, d_); } \
        if (col == 0) { s[row0 + (U)] = vs; t[row0 + (U)] = vn; } }
    RED(acc0, 0) RED(acc1, 1) RED(acc2, 2) RED(acc3, 3)
    #undef RED
}

/* ---------------- kernel 2: global max of t ---------------------------------- */
__global__ __launch_bounds__(1024) void tmax_kernel(
    const float* __restrict__ t, float* __restrict__ tmax)
{
    __shared__ float red[16];
    float m = -3e38f;
    for (int i = threadIdx.x; i < Nn; i += 1024) m = fmaxf(m, t[i]);
    #pragma unroll
    for (int d = 32; d; d >>= 1) m = fmaxf(m, __shfl_xor(m, d));
    if ((threadIdx.x & 63) == 0) red[threadIdx.x >> 6] = m;
    __syncthreads();
    if (threadIdx.x < 16) {
        m = red[threadIdx.x];
        #pragma unroll
        for (int d = 8; d; d >>= 1) m = fmaxf(m, __shfl_xor(m, d));
        if (threadIdx.x == 0) *tmax = m;
    }
}

/* ---------------- kernel 3: main fused attention ------------------------------
   grid (313, 2), block 256. Each block: rows [i0, i0+32), tiles of 64 j.
   p(i,j) = adj>0 ? exp(leaky((s_i + t_j)*M) - m_i) : 0,  m_i = max(0, s_i+tmax).
   Accumulates unnormalized h' into hp_acc (= d_out) and denominators via atomics. */
__global__ __launch_bounds__(256, 2) void gat_main_kernel(
    const float* __restrict__ adj, const float* __restrict__ Mm,
    const float* __restrict__ h,   const float* __restrict__ sv,
    const float* __restrict__ tv,  const float* __restrict__ tmaxp,
    float* __restrict__ den_acc,   float* __restrict__ hp_acc)
{
    __shared__ __align__(16) float hT[TJ][OUTF];       /* 16 KB  */
    __shared__ __align__(16) float Pl[TI][TJ + 4];     /* 8.5 KB, pad kills bank conflicts */

    const int tid = threadIdx.x;
    const int i0  = blockIdx.x * TI;
    const int tlo = (blockIdx.y == 0) ? 0      : TILES0;
    const int thi = (blockIdx.y == 0) ? TILES0 : NTILES;

    /* P-compute mapping: 32 rows x 8 j-chunks */
    const int rr  = tid >> 3;
    const int jc  = tid & 7;
    const int prow = i0 + rr;
    const bool rowok = prow < Nn;
    const float si = rowok ? sv[prow] : 0.0f;
    const float mc = fmaxf(0.0f, si + *tmaxp) * LOG2E;  /* shift, in log2 units */
    const float* aRow = adj + (size_t)prow * Nn;
    const float* mRow = Mm  + (size_t)prow * Nn;

    /* h-stage mapping: 16 row-slots x 16 col-quads, 4 reps */
    const int hr = tid >> 4;
    const int hc = (tid & 15) << 2;

    /* inner mapping: rows (r1, r1+16) x 4 outputs */
    const int r1 = tid >> 4;
    const int g4 = (tid & 15) << 2;

    const float4 z4 = make_float4(0.f, 0.f, 0.f, 0.f);
    float4 ph0 = z4, ph1 = z4, ph2 = z4, ph3 = z4;
    float4 pa0 = z4, pa1 = z4, pm0 = z4, pm1 = z4, pt0 = z4, pt1 = z4;
    float4 aA = z4, aB = z4;
    float denacc = 0.0f;

    auto prefetch = [&](int tile) {
        const int j0 = tile * TJ;
        ph0 = (j0 + hr      < Nn) ? *(const float4*)(h + (j0 + hr     ) * OUTF + hc) : z4;
        ph1 = (j0 + hr + 16 < Nn) ? *(const float4*)(h + (j0 + hr + 16) * OUTF + hc) : z4;
        ph2 = (j0 + hr + 32 < Nn) ? *(const float4*)(h + (j0 + hr + 32) * OUTF + hc) : z4;
        ph3 = (j0 + hr + 48 < Nn) ? *(const float4*)(h + (j0 + hr + 48) * OUTF + hc) : z4;
        const int jl = j0 + (jc << 3);
        if (rowok && jl + 7 < Nn) {
            pa0 = *(const float4*)(aRow + jl); pa1 = *(const float4*)(aRow + jl + 4);
            pm0 = *(const float4*)(mRow + jl); pm1 = *(const float4*)(mRow + jl + 4);
            pt0 = *(const float4*)(tv   + jl); pt1 = *(const float4*)(tv   + jl + 4);
        } else {
            pa0 = pa1 = pm0 = pm1 = pt0 = pt1 = z4;
            if (rowok) {
                #define LD1(dst, base, off) if ((jl + (off)) < Nn) dst = (base)[jl + (off)]
                LD1(pa0.x, aRow, 0); LD1(pa0.y, aRow, 1); LD1(pa0.z, aRow, 2); LD1(pa0.w, aRow, 3);
                LD1(pa1.x, aRow, 4); LD1(pa1.y, aRow, 5); LD1(pa1.z, aRow, 6); LD1(pa1.w, aRow, 7);
                LD1(pm0.x, mRow, 0); LD1(pm0.y, mRow, 1); LD1(pm0.z, mRow, 2); LD1(pm0.w, mRow, 3);
                LD1(pm1.x, mRow, 4); LD1(pm1.y, mRow, 5); LD1(pm1.z, mRow, 6); LD1(pm1.w, mRow, 7);
                LD1(pt0.x, tv,   0); LD1(pt0.y, tv,   1); LD1(pt0.z, tv,   2); LD1(pt0.w, tv,   3);
                LD1(pt1.x, tv,   4); LD1(pt1.y, tv,   5); LD1(pt1.z, tv,   6); LD1(pt1.w, tv,   7);
                #undef LD1
            }
        }
    };

    #define PC(dst, av, mv, tvv) { \
        float e_ = (si + (tvv)) * (mv); \
        float l_ = fmaxf(e_, ALPHA * e_); \
        dst = ((av) > 0.0f) ? exp2f(fmaf(l_, LOG2E, -mc)) : 0.0f; }

    prefetch(tlo);
    for (int tile = tlo; tile < thi; ++tile) {
        __syncthreads();   /* previous inner loop done reading LDS */

        *(float4*)&hT[hr     ][hc] = ph0;
        *(float4*)&hT[hr + 16][hc] = ph1;
        *(float4*)&hT[hr + 32][hc] = ph2;
        *(float4*)&hT[hr + 48][hc] = ph3;

        float4 p40, p41;
        PC(p40.x, pa0.x, pm0.x, pt0.x); PC(p40.y, pa0.y, pm0.y, pt0.y);
        PC(p40.z, pa0.z, pm0.z, pt0.z); PC(p40.w, pa0.w, pm0.w, pt0.w);
        PC(p41.x, pa1.x, pm1.x, pt1.x); PC(p41.y, pa1.y, pm1.y, pt1.y);
        PC(p41.z, pa1.z, pm1.z, pt1.z); PC(p41.w, pa1.w, pm1.w, pt1.w);
        *(float4*)&Pl[rr][(jc << 3)    ] = p40;
        *(float4*)&Pl[rr][(jc << 3) + 4] = p41;
        denacc += ((p40.x + p40.y) + (p40.z + p40.w)) + ((p41.x + p41.y) + (p41.z + p41.w));

        __syncthreads();   /* staging visible */

        if (tile + 1 < thi) prefetch(tile + 1);  /* HBM loads fly during inner loop */

        #pragma unroll
        for (int q = 0; q < TJ / 4; ++q) {
            const float4 pA = *(const float4*)&Pl[r1     ][q << 2];
            const float4 pB = *(const float4*)&Pl[r1 + 16][q << 2];
            const float4 h0 = *(const float4*)&hT[(q << 2)    ][g4];
            const float4 h1 = *(const float4*)&hT[(q << 2) + 1][g4];
            const float4 h2 = *(const float4*)&hT[(q << 2) + 2][g4];
            const float4 h3 = *(const float4*)&hT[(q << 2) + 3][g4];
            fma4(aA, pA.x, h0); fma4(aB, pB.x, h0);
            fma4(aA, pA.y, h1); fma4(aB, pB.y, h1);
            fma4(aA, pA.z, h2); fma4(aB, pB.z, h2);
            fma4(aA, pA.w, h3); fma4(aB, pB.w, h3);
        }
    }
    #undef PC

    /* denominator: reduce over the 8 jc-lanes of each row (lanes rr*8..rr*8+7) */
    float d = denacc;
    d += __shfl_xor(d, 1); d += __shfl_xor(d, 2); d += __shfl_xor(d, 4);
    if (rowok && jc == 0) atomicAdd(&den_acc[prow], d);

    const int rowa = i0 + r1, rowb = rowa + 16;
    if (rowa < Nn) {
        float* dst = hp_acc + rowa * OUTF + g4;
        atomicAdd(dst + 0, aA.x); atomicAdd(dst + 1, aA.y);
        atomicAdd(dst + 2, aA.z); atomicAdd(dst + 3, aA.w);
    }
    if (rowb < Nn) {
        float* dst = hp_acc + rowb * OUTF + g4;
        atomicAdd(dst + 0, aB.x); atomicAdd(dst + 1, aB.y);
        atomicAdd(dst + 2, aB.z); atomicAdd(dst + 3, aB.w);
    }
}

/* ---------------- kernel 4: normalize + ELU, in place in d_out ---------------- */
__global__ __launch_bounds__(256) void finalize_kernel(
    const float* __restrict__ den, float* __restrict__ out)
{
    const int idx = blockIdx.x * 256 + threadIdx.x;
    const float v = out[idx] / den[idx >> 6];
    out[idx] = (v > 0.0f) ? v : expm1f(v);
}

extern "C" void kernel_launch(void* const* d_in, const int* in_sizes, int n_in,
                              void* d_out, int out_size, void* d_ws, size_t ws_size,
                              hipStream_t stream) {
    const float* x        = (const float*)d_in[0];
    const float* adj      = (const float*)d_in[1];
    const float* Mm       = (const float*)d_in[2];
    const float* W        = (const float*)d_in[3];
    const float* a_self   = (const float*)d_in[4];
    const float* a_neighs = (const float*)d_in[5];

    float* out  = (float*)d_out;
    float* ws   = (float*)d_ws;
    float* h    = ws + WS_H;
    float* s    = ws + WS_S;
    float* t    = ws + WS_T;
    float* tmax = ws + WS_TMAX;
    float* den  = ws + WS_DEN;

    /* accumulators must start at zero every call (harness doesn't re-poison) */
    hipMemsetAsync(den, 0, Nn * sizeof(float), stream);
    hipMemsetAsync(d_out, 0, (size_t)out_size * sizeof(float), stream);

    hgemm_kernel<<<Nn / 16, 256, 0, stream>>>(x, W, a_self, a_neighs, h, s, t);
    tmax_kernel<<<1, 1024, 0, stream>>>(t, tmax);
    gat_main_kernel<<<dim3((Nn + TI - 1) / TI, 2), 256, 0, stream>>>(
        adj, Mm, h, s, t, tmax, den, out);
    finalize_kernel<<<(Nn * OUTF) / 256, 256, 0, stream>>>(den, out);
}

// Round 2
// 254.331 us; speedup vs baseline: 1.6759x; 1.6759x over previous
//
#include <hip/hip_runtime.h>
#include <math.h>

#define Nn 10000
#define NPAD 10048              /* j-padding for bf16 transposed h, mult of 64 */
#define INF_ 512
#define OUTF 64
#define ALPHA 0.2f
#define LOG2E 1.4426950408889634f

#define TI 32
#define TJ 64
#define NTILES ((Nn + TJ - 1) / TJ)   /* 157 */
#define YS 4
#define TPC ((NTILES + YS - 1) / YS)  /* 40 */

typedef __attribute__((ext_vector_type(8))) short bfrag;   /* 8 bf16 = 4 VGPR */
typedef __attribute__((ext_vector_type(4))) float facc;    /* 4 f32 acc */

/* workspace layout (float offsets) */
#define WS_S    0
#define WS_T    (Nn)
#define WS_TMAX (2*Nn)
#define WS_DEN  (2*Nn + 16)
#define WS_HBT  (3*Nn + 16)     /* ushort[OUTF][NPAD], 16B-aligned (offset 120064B) */

__device__ __forceinline__ unsigned short f2bf(float f) {
    unsigned int u = __float_as_uint(f);
    u += 0x7fffu + ((u >> 16) & 1u);          /* RNE; inputs finite */
    return (unsigned short)(u >> 16);
}
__device__ __forceinline__ unsigned int pk2(float a, float b) {
    return (unsigned int)f2bf(a) | ((unsigned int)f2bf(b) << 16);
}

/* ---- kernel 1: h = x@W; emit bf16 h^T, plus s = h@a_self, t = h@a_neighs ---- */
__global__ __launch_bounds__(256) void hgemm_kernel(
    const float* __restrict__ x, const float* __restrict__ W,
    const float* __restrict__ a_self, const float* __restrict__ a_neighs,
    unsigned short* __restrict__ hbfT, float* __restrict__ s, float* __restrict__ t)
{
    const int col  = threadIdx.x & 63;
    const int wid  = threadIdx.x >> 6;
    const int row0 = blockIdx.x * 16 + wid * 4;
    const float* x0 = x + row0 * INF_;

    float acc0 = 0.f, acc1 = 0.f, acc2 = 0.f, acc3 = 0.f;
    #pragma unroll 4
    for (int k4 = 0; k4 < INF_ / 4; ++k4) {
        const int k = k4 << 2;
        const float w0 = W[(k    ) * OUTF + col];
        const float w1 = W[(k + 1) * OUTF + col];
        const float w2 = W[(k + 2) * OUTF + col];
        const float w3 = W[(k + 3) * OUTF + col];
        const float4 xa = *(const float4*)(x0 +          k);
        const float4 xb = *(const float4*)(x0 +   INF_ + k);
        const float4 xc = *(const float4*)(x0 + 2*INF_ + k);
        const float4 xd = *(const float4*)(x0 + 3*INF_ + k);
        acc0 = fmaf(xa.x,w0, fmaf(xa.y,w1, fmaf(xa.z,w2, fmaf(xa.w,w3, acc0))));
        acc1 = fmaf(xb.x,w0, fmaf(xb.y,w1, fmaf(xb.z,w2, fmaf(xb.w,w3, acc1))));
        acc2 = fmaf(xc.x,w0, fmaf(xc.y,w1, fmaf(xc.z,w2, fmaf(xc.w,w3, acc2))));
        acc3 = fmaf(xd.x,w0, fmaf(xd.y,w1, fmaf(xd.z,w2, fmaf(xd.w,w3, acc3))));
    }
    /* transposed bf16 h for MFMA B-operand staging: hbfT[col][row] */
    ushort4 hb;
    hb.x = f2bf(acc0); hb.y = f2bf(acc1); hb.z = f2bf(acc2); hb.w = f2bf(acc3);
    *(ushort4*)(hbfT + (size_t)col * NPAD + row0) = hb;

    const float as = a_self[col], an = a_neighs[col];
    #define RED(ACC, U) { \
        float vs = (ACC) * as, vn = (ACC) * an; \
        _Pragma("unroll") \
        for (int d_ = 32; d_; d_ >>= 1) { vs += __shfl_xor(vs, d_); vn += __shfl_xor(vn, d_); } \
        if (col == 0) { s[row0 + (U)] = vs; t[row0 + (U)] = vn; } }
    RED(acc0, 0) RED(acc1, 1) RED(acc2, 2) RED(acc3, 3)
    #undef RED
}

/* ---- kernel 2: global max of t ---- */
__global__ __launch_bounds__(1024) void tmax_kernel(
    const float* __restrict__ t, float* __restrict__ tmax)
{
    __shared__ float red[16];
    float m = -3e38f;
    for (int i = threadIdx.x; i < Nn; i += 1024) m = fmaxf(m, t[i]);
    #pragma unroll
    for (int d = 32; d; d >>= 1) m = fmaxf(m, __shfl_xor(m, d));
    if ((threadIdx.x & 63) == 0) red[threadIdx.x >> 6] = m;
    __syncthreads();
    if (threadIdx.x < 16) {
        m = red[threadIdx.x];
        #pragma unroll
        for (int d = 8; d; d >>= 1) m = fmaxf(m, __shfl_xor(m, d));
        if (threadIdx.x == 0) *tmax = m;
    }
}

/* ---- kernel 3: fused attention, PV via bf16 MFMA --------------------------
   grid (313, 4), block 256 (4 waves). Rows [i0,i0+32), tile TJ=64 j.
   P fp32 on VALU -> bf16 to LDS; h^T bf16 tile to LDS; PV = 8x 16x16x32 MFMA. */
__global__ __launch_bounds__(256, 4) void gat_main_kernel(
    const float* __restrict__ adj, const float* __restrict__ Mm,
    const unsigned short* __restrict__ hbfT, const float* __restrict__ sv,
    const float* __restrict__ tv, const float* __restrict__ tmaxp,
    float* __restrict__ den_acc, float* __restrict__ hp_acc)
{
    __shared__ __align__(16) unsigned short hTl[OUTF][TJ + 8];  /* 9216 B, stride 144B */
    __shared__ __align__(16) unsigned short Pl[TI][TJ + 8];     /* 4608 B */

    const int tid = threadIdx.x;
    const int i0  = blockIdx.x * TI;
    const int tlo = blockIdx.y * TPC;
    const int thi = min(NTILES, tlo + TPC);

    /* P-compute mapping: 32 rows x 8 j-granules */
    const int rr = tid >> 3, jc = tid & 7;
    const int prow = i0 + rr;
    const bool rowok = prow < Nn;
    const float si = rowok ? sv[prow] : 0.0f;
    const float mc = fmaxf(0.0f, si + *tmaxp) * LOG2E;
    const float* aRow = adj + (size_t)prow * Nn;
    const float* mRow = Mm  + (size_t)prow * Nn;

    /* h-stage mapping: 64 cols x 4 segments of 16 j */
    const int hc_ = tid >> 2, hseg = tid & 3;
    const unsigned short* hsrc = hbfT + (size_t)hc_ * NPAD + hseg * 16;

    /* MFMA mapping: wave -> (row-block, col-block-pair) */
    const int lane = tid & 63, wv = tid >> 6;
    const int rb = wv & 1, cbp = wv >> 1;
    const unsigned short* aP  = &Pl[rb * 16 + (lane & 15)][(lane >> 4) * 8];
    const unsigned short* bP0 = &hTl[cbp * 32 + (lane & 15)][(lane >> 4) * 8];
    const unsigned short* bP1 = bP0 + 16 * (TJ + 8);

    facc accA = {0.f, 0.f, 0.f, 0.f}, accB = {0.f, 0.f, 0.f, 0.f};
    float denacc = 0.0f;

    const float4 z4 = make_float4(0.f, 0.f, 0.f, 0.f);
    float4 pa0 = z4, pa1 = z4, pm0 = z4, pm1 = z4, pt0 = z4, pt1 = z4;
    uint4 ph0 = make_uint4(0,0,0,0), ph1 = make_uint4(0,0,0,0);

    auto prefetch = [&](int tile) {
        const int j0 = tile * TJ;
        ph0 = *(const uint4*)(hsrc + j0);       /* bf16 h^T, zero-padded to NPAD */
        ph1 = *(const uint4*)(hsrc + j0 + 8);
        const int jl = j0 + (jc << 3);
        if (rowok && jl + 7 < Nn) {
            pa0 = *(const float4*)(aRow + jl); pa1 = *(const float4*)(aRow + jl + 4);
            pm0 = *(const float4*)(mRow + jl); pm1 = *(const float4*)(mRow + jl + 4);
            pt0 = *(const float4*)(tv   + jl); pt1 = *(const float4*)(tv   + jl + 4);
        } else {
            pa0 = pa1 = pm0 = pm1 = pt0 = pt1 = z4;
            if (rowok) {
                #define LD1(dst, base, off) if ((jl + (off)) < Nn) dst = (base)[jl + (off)]
                LD1(pa0.x, aRow, 0); LD1(pa0.y, aRow, 1); LD1(pa0.z, aRow, 2); LD1(pa0.w, aRow, 3);
                LD1(pa1.x, aRow, 4); LD1(pa1.y, aRow, 5); LD1(pa1.z, aRow, 6); LD1(pa1.w, aRow, 7);
                LD1(pm0.x, mRow, 0); LD1(pm0.y, mRow, 1); LD1(pm0.z, mRow, 2); LD1(pm0.w, mRow, 3);
                LD1(pm1.x, mRow, 4); LD1(pm1.y, mRow, 5); LD1(pm1.z, mRow, 6); LD1(pm1.w, mRow, 7);
                LD1(pt0.x, tv,   0); LD1(pt0.y, tv,   1); LD1(pt0.z, tv,   2); LD1(pt0.w, tv,   3);
                LD1(pt1.x, tv,   4); LD1(pt1.y, tv,   5); LD1(pt1.z, tv,   6); LD1(pt1.w, tv,   7);
                #undef LD1
            }
        }
    };

    #define PC(dst, av, mv, tvv) { \
        float e_ = (si + (tvv)) * (mv); \
        float l_ = fmaxf(e_, ALPHA * e_); \
        dst = ((av) > 0.0f) ? exp2f(fmaf(l_, LOG2E, -mc)) : 0.0f; }

    prefetch(tlo);
    for (int tile = tlo; tile < thi; ++tile) {
        __syncthreads();   /* previous MFMA phase done reading LDS */

        *(uint4*)&hTl[hc_][hseg * 16]     = ph0;
        *(uint4*)&hTl[hc_][hseg * 16 + 8] = ph1;

        float4 p40, p41;
        PC(p40.x, pa0.x, pm0.x, pt0.x); PC(p40.y, pa0.y, pm0.y, pt0.y);
        PC(p40.z, pa0.z, pm0.z, pt0.z); PC(p40.w, pa0.w, pm0.w, pt0.w);
        PC(p41.x, pa1.x, pm1.x, pt1.x); PC(p41.y, pa1.y, pm1.y, pt1.y);
        PC(p41.z, pa1.z, pm1.z, pt1.z); PC(p41.w, pa1.w, pm1.w, pt1.w);
        denacc += ((p40.x + p40.y) + (p40.z + p40.w)) + ((p41.x + p41.y) + (p41.z + p41.w));

        uint4 pw;
        pw.x = pk2(p40.x, p40.y); pw.y = pk2(p40.z, p40.w);
        pw.z = pk2(p41.x, p41.y); pw.w = pk2(p41.z, p41.w);
        *(uint4*)&Pl[rr][jc << 3] = pw;

        __syncthreads();   /* staging visible */

        if (tile + 1 < thi) prefetch(tile + 1);   /* HBM loads fly under MFMA */

        #pragma unroll
        for (int k0 = 0; k0 < TJ; k0 += 32) {
            const bfrag af = *(const bfrag*)(aP  + k0);
            const bfrag b0 = *(const bfrag*)(bP0 + k0);
            const bfrag b1 = *(const bfrag*)(bP1 + k0);
            accA = __builtin_amdgcn_mfma_f32_16x16x32_bf16(af, b0, accA, 0, 0, 0);
            accB = __builtin_amdgcn_mfma_f32_16x16x32_bf16(af, b1, accB, 0, 0, 0);
        }
    }
    #undef PC

    /* denominator: reduce the 8 jc-lanes of each row */
    float d = denacc;
    d += __shfl_xor(d, 1); d += __shfl_xor(d, 2); d += __shfl_xor(d, 4);
    if (rowok && jc == 0) atomicAdd(&den_acc[prow], d);

    /* C/D layout (16x16x32): col = lane&15, row = (lane>>4)*4 + reg */
    const int orow = i0 + rb * 16 + ((lane >> 4) << 2);
    const int oc   = cbp * 32 + (lane & 15);
    #pragma unroll
    for (int r = 0; r < 4; ++r) {
        if (orow + r < Nn) {
            atomicAdd(&hp_acc[(orow + r) * OUTF + oc],      accA[r]);
            atomicAdd(&hp_acc[(orow + r) * OUTF + oc + 16], accB[r]);
        }
    }
}

/* ---- kernel 4: normalize + ELU, in place in d_out ---- */
__global__ __launch_bounds__(256) void finalize_kernel(
    const float* __restrict__ den, float* __restrict__ out)
{
    const int idx = blockIdx.x * 256 + threadIdx.x;
    const float v = out[idx] / den[idx >> 6];
    out[idx] = (v > 0.0f) ? v : expm1f(v);
}

extern "C" void kernel_launch(void* const* d_in, const int* in_sizes, int n_in,
                              void* d_out, int out_size, void* d_ws, size_t ws_size,
                              hipStream_t stream) {
    const float* x        = (const float*)d_in[0];
    const float* adj      = (const float*)d_in[1];
    const float* Mm       = (const float*)d_in[2];
    const float* W        = (const float*)d_in[3];
    const float* a_self   = (const float*)d_in[4];
    const float* a_neighs = (const float*)d_in[5];

    float* out  = (float*)d_out;
    float* ws   = (float*)d_ws;
    float* s    = ws + WS_S;
    float* t    = ws + WS_T;
    float* tmax = ws + WS_TMAX;
    float* den  = ws + WS_DEN;
    unsigned short* hbfT = (unsigned short*)(ws + WS_HBT);

    /* accumulators + hbfT padding must be zeroed every call */
    hipMemsetAsync(den, 0, Nn * sizeof(float), stream);
    hipMemsetAsync(hbfT, 0, (size_t)OUTF * NPAD * sizeof(unsigned short), stream);
    hipMemsetAsync(d_out, 0, (size_t)out_size * sizeof(float), stream);

    hgemm_kernel<<<Nn / 16, 256, 0, stream>>>(x, W, a_self, a_neighs, hbfT, s, t);
    tmax_kernel<<<1, 1024, 0, stream>>>(t, tmax);
    gat_main_kernel<<<dim3((Nn + TI - 1) / TI, YS), 256, 0, stream>>>(
        adj, Mm, hbfT, s, t, tmax, den, out);
    finalize_kernel<<<(Nn * OUTF) / 256, 256, 0, stream>>>(den, out);
}